// Round 2
// baseline (214.118 us; speedup 1.0000x reference)
//
#include <hip/hip_runtime.h>
#include <hip/hip_fp16.h>
#include <stdint.h>

#define TOK 8192      // B*S
#define DIM 1024
#define NE 8
#define NTILE 136     // max row-tiles: 128 + 8 ragged

typedef short bf16x8 __attribute__((ext_vector_type(8)));
typedef float f32x4 __attribute__((ext_vector_type(4)));

__device__ __forceinline__ unsigned short f2bf(float f) {
  unsigned int u = __float_as_uint(f);
  u += 0x7FFFu + ((u >> 16) & 1u);
  return (unsigned short)(u >> 16);
}

__device__ __forceinline__ void gl_lds16(const void* g, void* l) {
  __builtin_amdgcn_global_load_lds(
      (__attribute__((address_space(1))) unsigned int*)(g),
      (__attribute__((address_space(3))) unsigned int*)(l), 16, 0, 0);
}

// One wave per token: convert x row to bf16 + gating dots (fp64 acc) + write picks.
// NO global atomics (R1: 16384 same-line fetch-adds = 207 us serial).
// R7: gW staged to LDS transposed [e][d] -> per i-iter 8 conflict-free
// ds_read_b128 instead of 128 scattered global dword loads per wave.
__global__ __launch_bounds__(256) void gate_kernel(
    const float* __restrict__ x, const float* __restrict__ gW,
    const float* __restrict__ gb, unsigned short* __restrict__ xb,
    int* __restrict__ eSel, float* __restrict__ wSel, int* __restrict__ cnt)
{
  if (blockIdx.x == 0 && threadIdx.x < NE) cnt[threadIdx.x] = 0;

  __shared__ float gWs[NE * DIM];   // 32 KB, [e][d]
#pragma unroll
  for (int h = 0; h < 8; ++h) {
    const int m = threadIdx.x + h * 256;       // float4 id over gW (2048)
    float4 v = ((const float4*)gW)[m];
    const int d = m >> 1, e0 = (m & 1) * 4;    // gW is [d][e]: elem 4m+c = (d, e0+c)
    gWs[(e0 + 0) * DIM + d] = v.x;
    gWs[(e0 + 1) * DIM + d] = v.y;
    gWs[(e0 + 2) * DIM + d] = v.z;
    gWs[(e0 + 3) * DIM + d] = v.w;
  }
  __syncthreads();

  const int wave = threadIdx.x >> 6;
  const int lane = threadIdx.x & 63;
  const int t = blockIdx.x * 4 + wave;
  const float4* xrow = (const float4*)(x + (size_t)t * DIM);
  ushort4* xbrow = (ushort4*)(xb + (size_t)t * DIM);

  double acc[NE];
#pragma unroll
  for (int e = 0; e < NE; ++e) acc[e] = 0.0;

#pragma unroll
  for (int i = 0; i < 4; ++i) {
    const int j = i * 64 + lane;         // float4 index within row (0..255)
    float4 v = xrow[j];
    ushort4 pk;
    pk.x = f2bf(v.x); pk.y = f2bf(v.y); pk.z = f2bf(v.z); pk.w = f2bf(v.w);
    xbrow[j] = pk;
#pragma unroll
    for (int e = 0; e < NE; ++e) {
      float4 gv = *(const float4*)&gWs[e * DIM + j * 4];
      acc[e] += (double)v.x * (double)gv.x + (double)v.y * (double)gv.y
              + (double)v.z * (double)gv.z + (double)v.w * (double)gv.w;
    }
  }
  // wave64 butterfly reduce (doubles)
#pragma unroll
  for (int off = 32; off > 0; off >>= 1) {
#pragma unroll
    for (int e = 0; e < NE; ++e)
      acc[e] += __shfl_xor(acc[e], off, 64);
  }

  if (lane == 0) {
    double s[NE];
#pragma unroll
    for (int e = 0; e < NE; ++e) {
      s[e] = acc[e] + (double)gb[e];
      if (s[e] < 1e-4) s[e] = 1e-4;     // clamp-min(EPS), TEMP=1
    }
    // top-2 by value on fp64 sums, ties -> lower index (strict > scan)
    int e0 = 0;
    for (int e = 1; e < NE; ++e) if (s[e] > s[e0]) e0 = e;
    int e1 = (e0 == 0) ? 1 : 0;
    for (int e = 0; e < NE; ++e) if (e != e0 && s[e] > s[e1]) e1 = e;
    // softmax + weights in fp32 (hardware exp)
    float m = (float)s[e0];             // e0 is the max
    float Z = 0.f, pf[NE];
#pragma unroll
    for (int e = 0; e < NE; ++e) { pf[e] = __expf((float)s[e] - m); Z += pf[e]; }
    float w0 = pf[e0] / Z; if (w0 < 0.1f) w0 = 0.1f;
    float w1 = pf[e1] / Z; if (w1 < 0.1f) w1 = 0.1f;
    const float inv = 0.5f / (w0 + w1);   // /total /K
    eSel[t * 2 + 0] = e0;
    eSel[t * 2 + 1] = e1;
    wSel[t * 2 + 0] = w0 * inv;
    wSel[t * 2 + 1] = w1 * inv;
  }
}

// Two-level scatter: LDS histogram per block (256 tokens), 8 global atomics per
// block for base offsets, then conflict-free placement. 256 global atomics total.
__global__ __launch_bounds__(256) void scatter_kernel(
    const int* __restrict__ eSel, const float* __restrict__ wSel,
    int* __restrict__ cnt, int* __restrict__ listTok, float* __restrict__ listW)
{
  __shared__ int lcnt[NE];
  __shared__ int base[NE];
  const int tid = threadIdx.x;
  if (tid < NE) lcnt[tid] = 0;
  __syncthreads();

  const int t = blockIdx.x * 256 + tid;
  const int e0 = eSel[t * 2 + 0];
  const int e1 = eSel[t * 2 + 1];
  const float w0 = wSel[t * 2 + 0];
  const float w1 = wSel[t * 2 + 1];
  const int l0 = atomicAdd(&lcnt[e0], 1);
  const int l1 = atomicAdd(&lcnt[e1], 1);
  __syncthreads();
  if (tid < NE) base[tid] = atomicAdd(&cnt[tid], lcnt[tid]);
  __syncthreads();

  const int p0 = base[e0] + l0;
  listTok[e0 * TOK + p0] = t * 2 + 0;   // token*2 + slot
  listW [e0 * TOK + p0] = w0;
  const int p1 = base[e1] + l1;
  listTok[e1 * TOK + p1] = t * 2 + 1;
  listW [e1 * TOK + p1] = w1;
}

// expert_W [e][d][f] fp32 -> Wt [e][f][d] bf16 (flat, layout the gemm staging
// uses). R8 rewrite: 64x64 LDS tiles, 2048 blocks (was 256 -> 1 block/CU,
// latency-bound), float4 coalesced loads (was scalar dword), packed uint
// (2xbf16) stores (was scalar 2B stores). <=2-way LDS conflicts (free, m136).
__global__ __launch_bounds__(256) void transpose_w(
    const float* __restrict__ W, unsigned short* __restrict__ Wt)
{
  __shared__ float t2[64][65];           // +1 pad
  const int b  = blockIdx.x;
  const int e  = b >> 8;                 // 256 tiles per expert
  const int db = (b >> 4) & 15;          // d (k) block
  const int fb = b & 15;                 // f block
  const int d0 = db * 64, f0 = fb * 64;
  const int tid = threadIdx.x;
  // load 64x64 fp32 tile: thread h-iter -> row idx>>4, float4 col idx&15
#pragma unroll
  for (int h = 0; h < 4; ++h) {
    const int idx = tid + h * 256;
    const int r = idx >> 4, c4 = idx & 15;
    float4 v = *(const float4*)&W[((size_t)e * DIM + d0 + r) * DIM + f0 + c4 * 4];
    t2[r][c4 * 4 + 0] = v.x;
    t2[r][c4 * 4 + 1] = v.y;
    t2[r][c4 * 4 + 2] = v.z;
    t2[r][c4 * 4 + 3] = v.w;
  }
  __syncthreads();
  // write transposed: f-row gets 64 d-values as 32 packed uints (128 B / row)
#pragma unroll
  for (int h = 0; h < 8; ++h) {
    const int o = tid + h * 256;
    const int f = o >> 5, k2 = (o & 31) * 2;
    const unsigned int lo = f2bf(t2[k2][f]);
    const unsigned int hi = f2bf(t2[k2 + 1][f]);
    *(unsigned int*)&Wt[((size_t)e * DIM + f0 + f) * DIM + d0 + k2] =
        lo | (hi << 16);
  }
}

// Grouped GEMM: 128(tokens) x 128(f) tile, BK=32, 16x16x32 bf16 MFMA.
// R8: T4 counted-vmcnt pipeline. The old 2-buffer loop ended every K-step in
// __syncthreads() == s_waitcnt vmcnt(0) drain (m97-structure stall, ~20%+ here
// since only 2 blocks/CU resident -> no TLP to hide it). Now: 4-buffer LDS
// ring staged 3 K-tiles ahead; barriers are raw s_barrier preceded by
// s_waitcnt vmcnt(8) lgkmcnt(0) -- 8 loads (2 tiles) stay in flight across
// every barrier, each load gets ~3 iterations (~1.9k cy) to cover ~900 cy HBM
// latency. Race-free: buffer overwritten at iter t is tile (t+4)%4 == t%4,
// whose reads all waves finished before the barrier just crossed (lgkmcnt(0)
// retires them); per-wave vmcnt + barrier => cross-wave visibility of t+1.
// Addressing/swizzle identical to R7 (bank conflicts measured 0).
__global__ __launch_bounds__(256) void moe_gemm(
    const unsigned short* __restrict__ xb, const unsigned short* __restrict__ Wt,
    const float* __restrict__ eb, const int* __restrict__ cnt,
    const int* __restrict__ listTok, const float* __restrict__ listW,
    __half* __restrict__ yslot)
{
  const int dId = blockIdx.x % NTILE;
  const int cT  = blockIdx.x / NTILE;
  int e = -1, r0 = 0, rows = 0, accT = 0;
#pragma unroll
  for (int ee = 0; ee < NE; ++ee) {
    const int c = cnt[ee];
    const int nt = (c + 127) >> 7;
    if (dId >= accT && dId < accT + nt) {
      e = ee; r0 = (dId - accT) * 128;
      rows = c - r0; if (rows > 128) rows = 128;
    }
    accT += nt;
  }
  if (e < 0) return;

  __shared__ __align__(16) unsigned short As[4][128 * 32];  // 4-deep ring, 32 KB
  __shared__ __align__(16) unsigned short Bs[4][128 * 32];  // 32 KB
  __shared__ int   tid_s[128];
  __shared__ float w_s[128];

  const int tid = threadIdx.x;
  if (tid < 128) {
    if (tid < rows) {
      tid_s[tid] = listTok[e * TOK + r0 + tid];
      w_s[tid]   = listW [e * TOK + r0 + tid];
    } else {
      tid_s[tid] = 0;     // safe dummy row (token 0) — never stored
      w_s[tid]   = 0.0f;
    }
  }
  __syncthreads();        // also drains the listTok/listW loads -> vmcnt clean

  const int w    = tid >> 6;
  const int lane = tid & 63;
  // Staging: lane i fills LDS quarter-slot (i&3) of tile-row w*32+(i>>2) [+16].
  // Swizzle: slot q holds GLOBAL quarter q ^ ((row>>1)&3) = q ^ ((lane>>3)&3).
  const int qsrc = (lane & 3) ^ ((lane >> 3) & 3);
  const int rA0  = w * 32 + (lane >> 2);
  const int rA1  = rA0 + 16;
  const unsigned short* srcA0 = xb + (size_t)(tid_s[rA0] >> 1) * DIM + qsrc * 8;
  const unsigned short* srcA1 = xb + (size_t)(tid_s[rA1] >> 1) * DIM + qsrc * 8;
  const unsigned short* srcB0 = Wt + ((size_t)e * DIM + cT * 128 + rA0) * DIM + qsrc * 8;
  const unsigned short* srcB1 = Wt + ((size_t)e * DIM + cT * 128 + rA1) * DIM + qsrc * 8;

  const int wr = w >> 1, wc = w & 1;
  const int mrow = lane & 15;
  const int qg   = lane >> 4;                      // global k-quarter consumed
  const int qsA  = (qg ^ ((mrow >> 1) & 3)) * 8;   // swizzled LDS offset (elems)

  f32x4 acc[4][4];
#pragma unroll
  for (int i = 0; i < 4; ++i)
#pragma unroll
    for (int j = 0; j < 4; ++j)
      acc[i][j] = {0.f, 0.f, 0.f, 0.f};

  // prologue: stage K-tiles 0,1,2 into ring slots 0,1,2 (12 loads in flight)
#pragma unroll
  for (int p = 0; p < 3; ++p) {
    unsigned short* a = &As[p][w * 1024];
    unsigned short* b = &Bs[p][w * 1024];
    gl_lds16(srcA0 + p * 32, a);
    gl_lds16(srcA1 + p * 32, a + 512);
    gl_lds16(srcB0 + p * 32, b);
    gl_lds16(srcB1 + p * 32, b + 512);
  }
  asm volatile("s_waitcnt vmcnt(8)" ::: "memory");   // tile 0 landed; 1,2 in flight
  __builtin_amdgcn_s_barrier();

  for (int kc = 0; kc < DIM / 32; ++kc) {
    const int cur = kc & 3;
    if (kc + 3 < DIM / 32) {            // stage tile kc+3 into ring slot (kc+3)&3
      const int k1 = (kc + 3) * 32;
      const int nb = (kc + 3) & 3;
      unsigned short* a = &As[nb][w * 1024];
      unsigned short* b = &Bs[nb][w * 1024];
      gl_lds16(srcA0 + k1, a);
      gl_lds16(srcA1 + k1, a + 512);
      gl_lds16(srcB0 + k1, b);
      gl_lds16(srcB1 + k1, b + 512);
    }
    bf16x8 af[4], bfr[4];
#pragma unroll
    for (int mt = 0; mt < 4; ++mt)
      af[mt] = *(const bf16x8*)&As[cur][(wr * 64 + mt * 16 + mrow) * 32 + qsA];
#pragma unroll
    for (int nt = 0; nt < 4; ++nt)
      bfr[nt] = *(const bf16x8*)&Bs[cur][(wc * 64 + nt * 16 + mrow) * 32 + qsA];
#pragma unroll
    for (int mt = 0; mt < 4; ++mt)
#pragma unroll
      for (int nt = 0; nt < 4; ++nt)
        acc[mt][nt] = __builtin_amdgcn_mfma_f32_16x16x32_bf16(
            af[mt], bfr[nt], acc[mt][nt], 0, 0, 0);
    // end-of-K-step: wait only until tile kc+1 is resident (counted, never a
    // full drain until the ring empties at the tail), then raw barrier.
    if (kc < DIM / 32 - 1) {
      if (kc < DIM / 32 - 3)
        asm volatile("s_waitcnt vmcnt(8) lgkmcnt(0)" ::: "memory");
      else if (kc == DIM / 32 - 3)
        asm volatile("s_waitcnt vmcnt(4) lgkmcnt(0)" ::: "memory");
      else
        asm volatile("s_waitcnt vmcnt(0) lgkmcnt(0)" ::: "memory");
      __builtin_amdgcn_s_barrier();
    }
  }

  // epilogue: C/D map col=lane&15, row=(lane>>4)*4+r
  const int colBase = cT * 128 + wc * 64 + mrow;
  float bias[4];
#pragma unroll
  for (int nt = 0; nt < 4; ++nt)
    bias[nt] = eb[(size_t)e * DIM + colBase + nt * 16];
#pragma unroll
  for (int mt = 0; mt < 4; ++mt) {
#pragma unroll
    for (int r = 0; r < 4; ++r) {
      const int rloc = wr * 64 + mt * 16 + (lane >> 4) * 4 + r;
      if (rloc < rows) {
        const int tk    = tid_s[rloc];
        const float wgt = w_s[rloc];
        __half* dst = yslot + ((size_t)(tk & 1) * TOK + (size_t)(tk >> 1)) * DIM;
#pragma unroll
        for (int nt = 0; nt < 4; ++nt)
          dst[colBase + nt * 16] = __float2half(wgt * (acc[mt][nt][r] + bias[nt]));
      }
    }
  }
}

__global__ __launch_bounds__(256) void combine(
    const __half* __restrict__ y0, const __half* __restrict__ y1,
    float4* __restrict__ out)
{
  const size_t i = (size_t)blockIdx.x * 256 + threadIdx.x;  // float4 index
  const ushort4 ua = ((const ushort4*)y0)[i];
  const ushort4 ub = ((const ushort4*)y1)[i];
  const __half* ah = (const __half*)&ua;
  const __half* bh = (const __half*)&ub;
  float4 o;
  o.x = __half2float(ah[0]) + __half2float(bh[0]);
  o.y = __half2float(ah[1]) + __half2float(bh[1]);
  o.z = __half2float(ah[2]) + __half2float(bh[2]);
  o.w = __half2float(ah[3]) + __half2float(bh[3]);
  out[i] = o;
}

extern "C" void kernel_launch(void* const* d_in, const int* in_sizes, int n_in,
                              void* d_out, int out_size, void* d_ws, size_t ws_size,
                              hipStream_t stream)
{
  const float* x  = (const float*)d_in[0];
  const float* gW = (const float*)d_in[1];
  const float* gb = (const float*)d_in[2];
  const float* eW = (const float*)d_in[3];
  const float* eb = (const float*)d_in[4];
  float* out = (float*)d_out;

  char* p = (char*)d_ws;
  unsigned short* xb = (unsigned short*)p;  p += (size_t)TOK * DIM * 2;       // 16 MB
  unsigned short* Wt = (unsigned short*)p;  p += (size_t)NE * DIM * DIM * 2;  // 16 MB
  __half* yslot = (__half*)p;               p += (size_t)2 * TOK * DIM * 2;   // 32 MB
  int* cnt = (int*)p;                       p += 256;
  int* listTok = (int*)p;                   p += (size_t)NE * TOK * 4;
  float* listW = (float*)p;                 p += (size_t)NE * TOK * 4;

  // eSel/wSel alias the head of yslot: consumed by scatter_kernel BEFORE
  // moe_gemm overwrites yslot (stream-ordered). Saves 128 KB of ws.
  int*   eSel = (int*)yslot;                        // TOK*2 ints = 64 KB
  float* wSel = (float*)((char*)yslot + TOK * 8);   // TOK*2 floats = 64 KB

  gate_kernel<<<TOK / 4, 256, 0, stream>>>(x, gW, gb, xb, eSel, wSel, cnt);
  scatter_kernel<<<TOK / 256, 256, 0, stream>>>(eSel, wSel, cnt, listTok, listW);
  transpose_w<<<NE * 256, 256, 0, stream>>>(eW, Wt);
  moe_gemm<<<NTILE * 8, 256, 0, stream>>>(xb, Wt, eb, cnt, listTok, listW, yslot);
  combine<<<TOK * DIM / 4 / 256, 256, 0, stream>>>(
      yslot, yslot + (size_t)TOK * DIM, (float4*)out);
}

// Round 3
// 208.324 us; speedup vs baseline: 1.0278x; 1.0278x over previous
//
#include <hip/hip_runtime.h>
#include <hip/hip_fp16.h>
#include <stdint.h>

#define TOK 8192      // B*S
#define DIM 1024
#define NE 8
#define NTILE 136     // max 128-row tiles: 128 + 8 ragged
#define NCT 4         // 1024 / 256 col-tiles

typedef short bf16x8 __attribute__((ext_vector_type(8)));
typedef float f32x4 __attribute__((ext_vector_type(4)));

__device__ __forceinline__ unsigned short f2bf(float f) {
  unsigned int u = __float_as_uint(f);
  u += 0x7FFFu + ((u >> 16) & 1u);
  return (unsigned short)(u >> 16);
}

__device__ __forceinline__ void gl_lds16(const void* g, void* l) {
  __builtin_amdgcn_global_load_lds(
      (__attribute__((address_space(1))) unsigned int*)(g),
      (__attribute__((address_space(3))) unsigned int*)(l), 16, 0, 0);
}

// One wave per token: convert x row to bf16 + gating dots (fp64 acc) + write picks.
__global__ __launch_bounds__(256) void gate_kernel(
    const float* __restrict__ x, const float* __restrict__ gW,
    const float* __restrict__ gb, unsigned short* __restrict__ xb,
    int* __restrict__ eSel, float* __restrict__ wSel, int* __restrict__ cnt)
{
  if (blockIdx.x == 0 && threadIdx.x < NE) cnt[threadIdx.x] = 0;

  __shared__ float gWs[NE * DIM];   // 32 KB, [e][d]
#pragma unroll
  for (int h = 0; h < 8; ++h) {
    const int m = threadIdx.x + h * 256;       // float4 id over gW (2048)
    float4 v = ((const float4*)gW)[m];
    const int d = m >> 1, e0 = (m & 1) * 4;    // gW is [d][e]: elem 4m+c = (d, e0+c)
    gWs[(e0 + 0) * DIM + d] = v.x;
    gWs[(e0 + 1) * DIM + d] = v.y;
    gWs[(e0 + 2) * DIM + d] = v.z;
    gWs[(e0 + 3) * DIM + d] = v.w;
  }
  __syncthreads();

  const int wave = threadIdx.x >> 6;
  const int lane = threadIdx.x & 63;
  const int t = blockIdx.x * 4 + wave;
  const float4* xrow = (const float4*)(x + (size_t)t * DIM);
  ushort4* xbrow = (ushort4*)(xb + (size_t)t * DIM);

  double acc[NE];
#pragma unroll
  for (int e = 0; e < NE; ++e) acc[e] = 0.0;

#pragma unroll
  for (int i = 0; i < 4; ++i) {
    const int j = i * 64 + lane;         // float4 index within row (0..255)
    float4 v = xrow[j];
    ushort4 pk;
    pk.x = f2bf(v.x); pk.y = f2bf(v.y); pk.z = f2bf(v.z); pk.w = f2bf(v.w);
    xbrow[j] = pk;
#pragma unroll
    for (int e = 0; e < NE; ++e) {
      float4 gv = *(const float4*)&gWs[e * DIM + j * 4];
      acc[e] += (double)v.x * (double)gv.x + (double)v.y * (double)gv.y
              + (double)v.z * (double)gv.z + (double)v.w * (double)gv.w;
    }
  }
  // wave64 butterfly reduce (doubles)
#pragma unroll
  for (int off = 32; off > 0; off >>= 1) {
#pragma unroll
    for (int e = 0; e < NE; ++e)
      acc[e] += __shfl_xor(acc[e], off, 64);
  }

  if (lane == 0) {
    double s[NE];
#pragma unroll
    for (int e = 0; e < NE; ++e) {
      s[e] = acc[e] + (double)gb[e];
      if (s[e] < 1e-4) s[e] = 1e-4;     // clamp-min(EPS), TEMP=1
    }
    // top-2 by value on fp64 sums, ties -> lower index (strict > scan)
    int e0 = 0;
    for (int e = 1; e < NE; ++e) if (s[e] > s[e0]) e0 = e;
    int e1 = (e0 == 0) ? 1 : 0;
    for (int e = 0; e < NE; ++e) if (e != e0 && s[e] > s[e1]) e1 = e;
    // softmax + weights in fp32 (hardware exp)
    float m = (float)s[e0];             // e0 is the max
    float Z = 0.f, pf[NE];
#pragma unroll
    for (int e = 0; e < NE; ++e) { pf[e] = __expf((float)s[e] - m); Z += pf[e]; }
    float w0 = pf[e0] / Z; if (w0 < 0.1f) w0 = 0.1f;
    float w1 = pf[e1] / Z; if (w1 < 0.1f) w1 = 0.1f;
    const float inv = 0.5f / (w0 + w1);   // /total /K
    eSel[t * 2 + 0] = e0;
    eSel[t * 2 + 1] = e1;
    wSel[t * 2 + 0] = w0 * inv;
    wSel[t * 2 + 1] = w1 * inv;
  }
}

// Two-level scatter: LDS histogram per block, 8 global atomics per block.
__global__ __launch_bounds__(256) void scatter_kernel(
    const int* __restrict__ eSel, const float* __restrict__ wSel,
    int* __restrict__ cnt, int* __restrict__ listTok, float* __restrict__ listW)
{
  __shared__ int lcnt[NE];
  __shared__ int base[NE];
  const int tid = threadIdx.x;
  if (tid < NE) lcnt[tid] = 0;
  __syncthreads();

  const int t = blockIdx.x * 256 + tid;
  const int e0 = eSel[t * 2 + 0];
  const int e1 = eSel[t * 2 + 1];
  const float w0 = wSel[t * 2 + 0];
  const float w1 = wSel[t * 2 + 1];
  const int l0 = atomicAdd(&lcnt[e0], 1);
  const int l1 = atomicAdd(&lcnt[e1], 1);
  __syncthreads();
  if (tid < NE) base[tid] = atomicAdd(&cnt[tid], lcnt[tid]);
  __syncthreads();

  const int p0 = base[e0] + l0;
  listTok[e0 * TOK + p0] = t * 2 + 0;   // token*2 + slot
  listW [e0 * TOK + p0] = w0;
  const int p1 = base[e1] + l1;
  listTok[e1 * TOK + p1] = t * 2 + 1;
  listW [e1 * TOK + p1] = w1;
}

// expert_W [e][d][f] fp32 -> Wt [e][f][d] bf16. 64x64 LDS tiles, 2048 blocks,
// float4 coalesced loads, packed uint (2xbf16) stores. (R8 version, kept.)
__global__ __launch_bounds__(256) void transpose_w(
    const float* __restrict__ W, unsigned short* __restrict__ Wt)
{
  __shared__ float t2[64][65];           // +1 pad
  const int b  = blockIdx.x;
  const int e  = b >> 8;                 // 256 tiles per expert
  const int db = (b >> 4) & 15;          // d (k) block
  const int fb = b & 15;                 // f block
  const int d0 = db * 64, f0 = fb * 64;
  const int tid = threadIdx.x;
#pragma unroll
  for (int h = 0; h < 4; ++h) {
    const int idx = tid + h * 256;
    const int r = idx >> 4, c4 = idx & 15;
    float4 v = *(const float4*)&W[((size_t)e * DIM + d0 + r) * DIM + f0 + c4 * 4];
    t2[r][c4 * 4 + 0] = v.x;
    t2[r][c4 * 4 + 1] = v.y;
    t2[r][c4 * 4 + 2] = v.z;
    t2[r][c4 * 4 + 3] = v.w;
  }
  __syncthreads();
#pragma unroll
  for (int h = 0; h < 8; ++h) {
    const int o = tid + h * 256;
    const int f = o >> 5, k2 = (o & 31) * 2;
    const unsigned int lo = f2bf(t2[k2][f]);
    const unsigned int hi = f2bf(t2[k2 + 1][f]);
    *(unsigned int*)&Wt[((size_t)e * DIM + f0 + f) * DIM + d0 + k2] =
        lo | (hi << 16);
  }
}

// ---------------------------------------------------------------------------
// R9 moe_gemm: 128(tokens) x 256(f) tile, BK=64, 8 waves (512 thr), 3-buffer
// LDS ring, 2 phases per K-tile (k-halves), counted vmcnt(9), setprio(1)
// around MFMA clusters (T3+T4+T5 stack; post-mortem: R8's counted vmcnt on
// the 128^2 2-barrier structure lost a resident block (3->2/CU) and
// regressed; here we commit to the 1-block/CU 8-wave regime where the
// phase schedule itself provides the overlap, per the m201 template).
//
// Per phase (t,h): 8 ds_read_b128 frags from buf[t%3][h]  ||  3 gl_lds16
// staging half (t+2,h) into buf[(t+2)%3][h]; s_barrier; setprio(1); 16 MFMA;
// setprio(0); s_waitcnt vmcnt(9); s_barrier. Prefetch distance = 4 phases;
// vmcnt drains only in the 3-phase tail (9 -> 6 -> 3 -> 0).
//
// Swizzle (64B rows, 4x16B slots, period 4): element at global quarter q of
// row r sits in LDS slot q^(r&3). Write side: gl_lds16 dest is linear
// (wave-uniform base + lane*16B); lane l covers row r0+(l>>2), slot l&3, so
// its GLOBAL source quarter is (l&3)^(r&3) (both-sides involution, m173).
// Read side: slot = qg^(mrow&3) -> verified balanced 8 accesses/bank.
// ---------------------------------------------------------------------------
#define WAITVM(n) asm volatile("s_waitcnt vmcnt(" #n ")" ::: "memory")

#define STG3(t, h, stb)                                                      \
  { const int off_ = (t) * 64 + (h) * 32;                                    \
    unsigned short* Ad_ = (unsigned short*)As + ((stb) * 2 + (h)) * (128 * 32) + w * 512;  \
    unsigned short* Bd_ = (unsigned short*)Bs + ((stb) * 2 + (h)) * (256 * 32) + w * 1024; \
    gl_lds16(srcA  + off_, Ad_);                                             \
    gl_lds16(srcB0 + off_, Bd_);                                             \
    gl_lds16(srcB1 + off_, Bd_ + 512); }

#define PHASE(t, h, bufv, stb, DO_STAGE, VMA)                                \
  { const unsigned short* Ab_ = (const unsigned short*)As + ((bufv) * 2 + (h)) * (128 * 32); \
    const unsigned short* Bb_ = (const unsigned short*)Bs + ((bufv) * 2 + (h)) * (256 * 32); \
    bf16x8 af[4], bfr[4];                                                    \
    _Pragma("unroll")                                                        \
    for (int mt = 0; mt < 4; ++mt)                                           \
      af[mt] = *(const bf16x8*)&Ab_[(wr * 64 + mt * 16 + mrow) * 32 + sA];   \
    _Pragma("unroll")                                                        \
    for (int nt = 0; nt < 4; ++nt)                                           \
      bfr[nt] = *(const bf16x8*)&Bb_[(wc * 64 + nt * 16 + mrow) * 32 + sA];  \
    if (DO_STAGE) { STG3((t) + 2, h, stb); }                                 \
    __builtin_amdgcn_s_barrier();                                            \
    __builtin_amdgcn_s_setprio(1);                                           \
    _Pragma("unroll")                                                        \
    for (int mt = 0; mt < 4; ++mt)                                           \
      _Pragma("unroll")                                                      \
      for (int nt = 0; nt < 4; ++nt)                                         \
        acc[mt][nt] = __builtin_amdgcn_mfma_f32_16x16x32_bf16(               \
            af[mt], bfr[nt], acc[mt][nt], 0, 0, 0);                          \
    __builtin_amdgcn_s_setprio(0);                                           \
    VMA;                                                                     \
    __builtin_amdgcn_s_barrier(); }

__global__ __launch_bounds__(512, 2) void moe_gemm(
    const unsigned short* __restrict__ xb, const unsigned short* __restrict__ Wt,
    const float* __restrict__ eb, const int* __restrict__ cnt,
    const int* __restrict__ listTok, const float* __restrict__ listW,
    __half* __restrict__ yslot)
{
  const int dId = blockIdx.x % NTILE;   // dId-major: cT siblings share XCD
  const int cT  = blockIdx.x / NTILE;
  int e = -1, r0 = 0, rows = 0, accT = 0;
#pragma unroll
  for (int ee = 0; ee < NE; ++ee) {
    const int c = cnt[ee];
    const int nt = (c + 127) >> 7;
    if (dId >= accT && dId < accT + nt) {
      e = ee; r0 = (dId - accT) * 128;
      rows = c - r0; if (rows > 128) rows = 128;
    }
    accT += nt;
  }
  if (e < 0) return;   // block-uniform exit, before any barrier

  // 3-ring x 2 k-halves: A 48 KB, B 96 KB, +1 KB lists = 145 KB (1 block/CU)
  __shared__ __align__(16) unsigned short As[3 * 2 * 128 * 32];
  __shared__ __align__(16) unsigned short Bs[3 * 2 * 256 * 32];
  __shared__ int   tid_s[128];
  __shared__ float w_s[128];

  const int tid = threadIdx.x;
  if (tid < 128) {
    if (tid < rows) {
      tid_s[tid] = listTok[e * TOK + r0 + tid];
      w_s[tid]   = listW [e * TOK + r0 + tid];
    } else {
      tid_s[tid] = 0;     // safe dummy row (token 0) — never stored
      w_s[tid]   = 0.0f;
    }
  }
  __syncthreads();        // drains vmcnt -> counted region starts clean

  const int w    = tid >> 6;           // wave 0..7
  const int lane = tid & 63;
  // Staging: A rows w*16..w*16+15 (1 call/half); B rows w*32..w*32+31 (2 calls)
  const int rA  = w * 16 + (lane >> 2);
  const int qA  = (lane & 3) ^ (rA & 3);
  const unsigned short* srcA = xb + (size_t)(tid_s[rA] >> 1) * DIM + qA * 8;
  const int rB0 = w * 32 + (lane >> 2);
  const int rB1 = rB0 + 16;                       // rB1&3 == rB0&3
  const int qB  = (lane & 3) ^ (rB0 & 3);
  const unsigned short* srcB0 = Wt + ((size_t)e * DIM + cT * 256 + rB0) * DIM + qB * 8;
  const unsigned short* srcB1 = Wt + ((size_t)e * DIM + cT * 256 + rB1) * DIM + qB * 8;

  const int wr = w >> 2, wc = w & 3;   // 2M x 4N wave grid, 64x64 out each
  const int mrow = lane & 15;
  const int qg   = lane >> 4;
  const int sA   = (qg ^ (mrow & 3)) * 8;   // swizzled 16B-slot offset (elems)

  f32x4 acc[4][4];
#pragma unroll
  for (int i = 0; i < 4; ++i)
#pragma unroll
    for (int j = 0; j < 4; ++j)
      acc[i][j] = {0.f, 0.f, 0.f, 0.f};

  // prologue: halves (0,0),(0,1) -> buf0, (1,0),(1,1) -> buf1; 12 in flight
  STG3(0, 0, 0); STG3(0, 1, 0); STG3(1, 0, 1); STG3(1, 1, 1);
  WAITVM(9);                    // half (0,0) resident; 9 outstanding
  __builtin_amdgcn_s_barrier();

  // steady state: tiles 0..13 stage tile t+2; vmcnt(9) holds the invariant
  int buf = 0, stb = 2;
#pragma unroll 1
  for (int t = 0; t < 14; ++t) {
    PHASE(t, 0, buf, stb, true, WAITVM(9));
    PHASE(t, 1, buf, stb, true, WAITVM(9));
    buf = (buf == 2) ? 0 : buf + 1;
    stb = (stb == 2) ? 0 : stb + 1;
  }
  // tail: tiles 14 (buf2) and 15 (buf0); drain 6 -> 3 -> 0
  PHASE(14, 0, 2, 0, false, WAITVM(6));
  PHASE(14, 1, 2, 0, false, WAITVM(3));
  PHASE(15, 0, 0, 0, false, WAITVM(0));
  PHASE(15, 1, 0, 0, false, ((void)0));

  // epilogue: C/D map col=lane&15, row=(lane>>4)*4+r (same as R7)
  const int colBase = cT * 256 + wc * 64 + mrow;
  float bias[4];
#pragma unroll
  for (int nt = 0; nt < 4; ++nt)
    bias[nt] = eb[(size_t)e * DIM + colBase + nt * 16];
#pragma unroll
  for (int mt = 0; mt < 4; ++mt) {
#pragma unroll
    for (int r = 0; r < 4; ++r) {
      const int rloc = wr * 64 + mt * 16 + (lane >> 4) * 4 + r;
      if (rloc < rows) {
        const int tk    = tid_s[rloc];
        const float wgt = w_s[rloc];
        __half* dst = yslot + ((size_t)(tk & 1) * TOK + (size_t)(tk >> 1)) * DIM;
#pragma unroll
        for (int nt = 0; nt < 4; ++nt)
          dst[colBase + nt * 16] = __float2half(wgt * (acc[mt][nt][r] + bias[nt]));
      }
    }
  }
}

__global__ __launch_bounds__(256) void combine(
    const __half* __restrict__ y0, const __half* __restrict__ y1,
    float4* __restrict__ out)
{
  const size_t i = (size_t)blockIdx.x * 256 + threadIdx.x;  // float4 index
  const ushort4 ua = ((const ushort4*)y0)[i];
  const ushort4 ub = ((const ushort4*)y1)[i];
  const __half* ah = (const __half*)&ua;
  const __half* bh = (const __half*)&ub;
  float4 o;
  o.x = __half2float(ah[0]) + __half2float(bh[0]);
  o.y = __half2float(ah[1]) + __half2float(bh[1]);
  o.z = __half2float(ah[2]) + __half2float(bh[2]);
  o.w = __half2float(ah[3]) + __half2float(bh[3]);
  out[i] = o;
}

extern "C" void kernel_launch(void* const* d_in, const int* in_sizes, int n_in,
                              void* d_out, int out_size, void* d_ws, size_t ws_size,
                              hipStream_t stream)
{
  const float* x  = (const float*)d_in[0];
  const float* gW = (const float*)d_in[1];
  const float* gb = (const float*)d_in[2];
  const float* eW = (const float*)d_in[3];
  const float* eb = (const float*)d_in[4];
  float* out = (float*)d_out;

  char* p = (char*)d_ws;
  unsigned short* xb = (unsigned short*)p;  p += (size_t)TOK * DIM * 2;       // 16 MB
  unsigned short* Wt = (unsigned short*)p;  p += (size_t)NE * DIM * DIM * 2;  // 16 MB
  __half* yslot = (__half*)p;               p += (size_t)2 * TOK * DIM * 2;   // 32 MB
  int* cnt = (int*)p;                       p += 256;
  int* listTok = (int*)p;                   p += (size_t)NE * TOK * 4;
  float* listW = (float*)p;                 p += (size_t)NE * TOK * 4;

  // eSel/wSel alias the head of yslot: consumed by scatter_kernel BEFORE
  // moe_gemm overwrites yslot (stream-ordered).
  int*   eSel = (int*)yslot;                        // TOK*2 ints = 64 KB
  float* wSel = (float*)((char*)yslot + TOK * 8);   // TOK*2 floats = 64 KB

  gate_kernel<<<TOK / 4, 256, 0, stream>>>(x, gW, gb, xb, eSel, wSel, cnt);
  scatter_kernel<<<TOK / 256, 256, 0, stream>>>(eSel, wSel, cnt, listTok, listW);
  transpose_w<<<NE * 256, 256, 0, stream>>>(eW, Wt);
  moe_gemm<<<NTILE * NCT, 512, 0, stream>>>(xb, Wt, eb, cnt, listTok, listW, yslot);
  combine<<<TOK * DIM / 4 / 256, 256, 0, stream>>>(
      yslot, yslot + (size_t)TOK * DIM, (float4*)out);
}

// Round 4
// 208.037 us; speedup vs baseline: 1.0292x; 1.0014x over previous
//
#include <hip/hip_runtime.h>
#include <hip/hip_fp16.h>
#include <stdint.h>

#define TOK 8192      // B*S
#define DIM 1024
#define NE 8
#define NT 72         // max 256-row tiles: 64 full + <=7 ragged (+1 safety)
#define NCT 8         // 1024 / 128 col-tiles

typedef short bf16x8 __attribute__((ext_vector_type(8)));
typedef float f32x4 __attribute__((ext_vector_type(4)));

__device__ __forceinline__ unsigned short f2bf(float f) {
  unsigned int u = __float_as_uint(f);
  u += 0x7FFFu + ((u >> 16) & 1u);
  return (unsigned short)(u >> 16);
}

__device__ __forceinline__ void gl_lds16(const void* g, void* l) {
  __builtin_amdgcn_global_load_lds(
      (__attribute__((address_space(1))) unsigned int*)(g),
      (__attribute__((address_space(3))) unsigned int*)(l), 16, 0, 0);
}

// One wave per token: convert x row to bf16 + gating dots (fp64 acc) + write picks.
__global__ __launch_bounds__(256) void gate_kernel(
    const float* __restrict__ x, const float* __restrict__ gW,
    const float* __restrict__ gb, unsigned short* __restrict__ xb,
    int* __restrict__ eSel, float* __restrict__ wSel, int* __restrict__ cnt)
{
  if (blockIdx.x == 0 && threadIdx.x < NE) cnt[threadIdx.x] = 0;

  __shared__ float gWs[NE * DIM];   // 32 KB, [e][d]
#pragma unroll
  for (int h = 0; h < 8; ++h) {
    const int m = threadIdx.x + h * 256;       // float4 id over gW (2048)
    float4 v = ((const float4*)gW)[m];
    const int d = m >> 1, e0 = (m & 1) * 4;    // gW is [d][e]: elem 4m+c = (d, e0+c)
    gWs[(e0 + 0) * DIM + d] = v.x;
    gWs[(e0 + 1) * DIM + d] = v.y;
    gWs[(e0 + 2) * DIM + d] = v.z;
    gWs[(e0 + 3) * DIM + d] = v.w;
  }
  __syncthreads();

  const int wave = threadIdx.x >> 6;
  const int lane = threadIdx.x & 63;
  const int t = blockIdx.x * 4 + wave;
  const float4* xrow = (const float4*)(x + (size_t)t * DIM);
  ushort4* xbrow = (ushort4*)(xb + (size_t)t * DIM);

  double acc[NE];
#pragma unroll
  for (int e = 0; e < NE; ++e) acc[e] = 0.0;

#pragma unroll
  for (int i = 0; i < 4; ++i) {
    const int j = i * 64 + lane;         // float4 index within row (0..255)
    float4 v = xrow[j];
    ushort4 pk;
    pk.x = f2bf(v.x); pk.y = f2bf(v.y); pk.z = f2bf(v.z); pk.w = f2bf(v.w);
    xbrow[j] = pk;
#pragma unroll
    for (int e = 0; e < NE; ++e) {
      float4 gv = *(const float4*)&gWs[e * DIM + j * 4];
      acc[e] += (double)v.x * (double)gv.x + (double)v.y * (double)gv.y
              + (double)v.z * (double)gv.z + (double)v.w * (double)gv.w;
    }
  }
  // wave64 butterfly reduce (doubles)
#pragma unroll
  for (int off = 32; off > 0; off >>= 1) {
#pragma unroll
    for (int e = 0; e < NE; ++e)
      acc[e] += __shfl_xor(acc[e], off, 64);
  }

  if (lane == 0) {
    double s[NE];
#pragma unroll
    for (int e = 0; e < NE; ++e) {
      s[e] = acc[e] + (double)gb[e];
      if (s[e] < 1e-4) s[e] = 1e-4;     // clamp-min(EPS), TEMP=1
    }
    // top-2 by value on fp64 sums, ties -> lower index (strict > scan)
    int e0 = 0;
    for (int e = 1; e < NE; ++e) if (s[e] > s[e0]) e0 = e;
    int e1 = (e0 == 0) ? 1 : 0;
    for (int e = 0; e < NE; ++e) if (e != e0 && s[e] > s[e1]) e1 = e;
    // softmax + weights in fp32 (hardware exp)
    float m = (float)s[e0];             // e0 is the max
    float Z = 0.f, pf[NE];
#pragma unroll
    for (int e = 0; e < NE; ++e) { pf[e] = __expf((float)s[e] - m); Z += pf[e]; }
    float w0 = pf[e0] / Z; if (w0 < 0.1f) w0 = 0.1f;
    float w1 = pf[e1] / Z; if (w1 < 0.1f) w1 = 0.1f;
    const float inv = 0.5f / (w0 + w1);   // /total /K
    eSel[t * 2 + 0] = e0;
    eSel[t * 2 + 1] = e1;
    wSel[t * 2 + 0] = w0 * inv;
    wSel[t * 2 + 1] = w1 * inv;
  }
}

// Two-level scatter: LDS histogram per block, 8 global atomics per block.
__global__ __launch_bounds__(256) void scatter_kernel(
    const int* __restrict__ eSel, const float* __restrict__ wSel,
    int* __restrict__ cnt, int* __restrict__ listTok, float* __restrict__ listW)
{
  __shared__ int lcnt[NE];
  __shared__ int base[NE];
  const int tid = threadIdx.x;
  if (tid < NE) lcnt[tid] = 0;
  __syncthreads();

  const int t = blockIdx.x * 256 + tid;
  const int e0 = eSel[t * 2 + 0];
  const int e1 = eSel[t * 2 + 1];
  const float w0 = wSel[t * 2 + 0];
  const float w1 = wSel[t * 2 + 1];
  const int l0 = atomicAdd(&lcnt[e0], 1);
  const int l1 = atomicAdd(&lcnt[e1], 1);
  __syncthreads();
  if (tid < NE) base[tid] = atomicAdd(&cnt[tid], lcnt[tid]);
  __syncthreads();

  const int p0 = base[e0] + l0;
  listTok[e0 * TOK + p0] = t * 2 + 0;   // token*2 + slot
  listW [e0 * TOK + p0] = w0;
  const int p1 = base[e1] + l1;
  listTok[e1 * TOK + p1] = t * 2 + 1;
  listW [e1 * TOK + p1] = w1;
}

// expert_W [e][d][f] fp32 -> Wt [e][f][d] bf16. 64x64 LDS tiles, 2048 blocks,
// float4 coalesced loads, packed uint (2xbf16) stores.
__global__ __launch_bounds__(256) void transpose_w(
    const float* __restrict__ W, unsigned short* __restrict__ Wt)
{
  __shared__ float t2[64][65];           // +1 pad
  const int b  = blockIdx.x;
  const int e  = b >> 8;                 // 256 tiles per expert
  const int db = (b >> 4) & 15;          // d (k) block
  const int fb = b & 15;                 // f block
  const int d0 = db * 64, f0 = fb * 64;
  const int tid = threadIdx.x;
#pragma unroll
  for (int h = 0; h < 4; ++h) {
    const int idx = tid + h * 256;
    const int r = idx >> 4, c4 = idx & 15;
    float4 v = *(const float4*)&W[((size_t)e * DIM + d0 + r) * DIM + f0 + c4 * 4];
    t2[r][c4 * 4 + 0] = v.x;
    t2[r][c4 * 4 + 1] = v.y;
    t2[r][c4 * 4 + 2] = v.z;
    t2[r][c4 * 4 + 3] = v.w;
  }
  __syncthreads();
#pragma unroll
  for (int h = 0; h < 8; ++h) {
    const int o = tid + h * 256;
    const int f = o >> 5, k2 = (o & 31) * 2;
    const unsigned int lo = f2bf(t2[k2][f]);
    const unsigned int hi = f2bf(t2[k2 + 1][f]);
    *(unsigned int*)&Wt[((size_t)e * DIM + f0 + f) * DIM + d0 + k2] =
        lo | (hi << 16);
  }
}

// ---------------------------------------------------------------------------
// R10 moe_gemm: 256(tokens) x 128(f) tile, 4 waves, WAVE-TILE 128x64 (8x4
// fragments), BK=32, 3-buffer ring, counted vmcnt(6).
//
// Post-mortem R7/R8/R9 (all ~17% MfmaUtil): the 4x4 wave-tile gives only
// 32 FLOP per LDS byte -> per-CU LDS traffic (read 512cy + stage 190cy)
// >= MFMA demand (621cy). Schedule tweaks can't fix an LDS-BW-bound inner
// loop. 8x4 fragments: 12 b128 reads feed 32 MFMA = 42.7 FLOP/B ->
// MFMA 1242cy vs LDS ~1024cy per phase -> compute-bound with headroom.
// 2 blocks/CU (74KB LDS, launch_bounds(256,2) caps VGPR at 256) restores
// cross-block TLP that R9's 1-block regime lost.
//
// Swizzle (64B rows, 4x16B slots): REVERTED to R7's verified conflict-free
// form. LDS slot q of row r holds global quarter q^((r>>1)&3). Write side:
// gl_lds16 dest linear; lane l -> row r0+(l>>2), slot l&3 -> source quarter
// (l&3)^((l>>3)&3) (r0 multiple of 16). Read side: slot = qg^((mrow>>1)&3);
// 8-lane groups cover all 32 banks exactly (R9's (mrow&3) variant aliased
// mrow and mrow+4 -> the measured 4.3M conflicts).
//
// Ring-3, prefetch 2 K-tiles ahead: stage(kt+2) during kt; end-of-iter
// vmcnt(6) retires tile kt+1's 6 calls, leaves kt+2's 6 in flight. The
// buffer staged at kt ((kt+2)%3) was last read at kt-1; those reads were
// consumed by MFMA before the end-of-(kt-1) barrier, and the DMA writes
// land after issue (post-barrier) -> race-free.
// ---------------------------------------------------------------------------
#define WAITVM(n) asm volatile("s_waitcnt vmcnt(" #n ")" ::: "memory")

#define STG(kt, bs)                                                          \
  { const int off_ = (kt) * 32;                                              \
    gl_lds16(srcA0 + off_, &As[bs][w * 2048 + 0]);                           \
    gl_lds16(srcA1 + off_, &As[bs][w * 2048 + 512]);                         \
    gl_lds16(srcA2 + off_, &As[bs][w * 2048 + 1024]);                        \
    gl_lds16(srcA3 + off_, &As[bs][w * 2048 + 1536]);                        \
    gl_lds16(srcB0 + off_, &Bs[bs][w * 1024 + 0]);                           \
    gl_lds16(srcB1 + off_, &Bs[bs][w * 1024 + 512]); }

#define CMP(bs)                                                              \
  { const unsigned short* Ab_ = &As[bs][0];                                  \
    const unsigned short* Bb_ = &Bs[bs][0];                                  \
    bf16x8 af[8], bfr[4];                                                    \
    _Pragma("unroll")                                                        \
    for (int mt = 0; mt < 8; ++mt)                                           \
      af[mt] = *(const bf16x8*)&Ab_[rdA + mt * 512];                         \
    _Pragma("unroll")                                                        \
    for (int nt = 0; nt < 4; ++nt)                                           \
      bfr[nt] = *(const bf16x8*)&Bb_[rdB + nt * 512];                        \
    __builtin_amdgcn_s_setprio(1);                                           \
    _Pragma("unroll")                                                        \
    for (int mt = 0; mt < 8; ++mt)                                           \
      _Pragma("unroll")                                                      \
      for (int nt = 0; nt < 4; ++nt)                                         \
        acc[mt][nt] = __builtin_amdgcn_mfma_f32_16x16x32_bf16(               \
            af[mt], bfr[nt], acc[mt][nt], 0, 0, 0);                          \
    __builtin_amdgcn_s_setprio(0); }

__global__ __launch_bounds__(256, 2) void moe_gemm(
    const unsigned short* __restrict__ xb, const unsigned short* __restrict__ Wt,
    const float* __restrict__ eb, const int* __restrict__ cnt,
    const int* __restrict__ listTok, const float* __restrict__ listW,
    __half* __restrict__ yslot)
{
  const int dId = blockIdx.x % NT;   // dId-major; NT%8==0 -> cT siblings share XCD
  const int cT  = blockIdx.x / NT;
  int e = -1, r0 = 0, rows = 0, accT = 0;
#pragma unroll
  for (int ee = 0; ee < NE; ++ee) {
    const int c = cnt[ee];
    const int nt = (c + 255) >> 8;
    if (dId >= accT && dId < accT + nt) {
      e = ee; r0 = (dId - accT) * 256;
      rows = c - r0; if (rows > 256) rows = 256;
    }
    accT += nt;
  }
  if (e < 0) return;   // block-uniform exit, before any barrier

  // ring-3: A 3x16KB, B 3x8KB, lists 2KB = 74KB -> 2 blocks/CU
  __shared__ __align__(16) unsigned short As[3][256 * 32];
  __shared__ __align__(16) unsigned short Bs[3][128 * 32];
  __shared__ int   tid_s[256];
  __shared__ float w_s[256];

  const int tid = threadIdx.x;
  if (tid < rows) {
    tid_s[tid] = listTok[e * TOK + r0 + tid];
    w_s[tid]   = listW [e * TOK + r0 + tid];
  } else {
    tid_s[tid] = 0;     // safe dummy row (token 0) — never stored
    w_s[tid]   = 0.0f;
  }
  __syncthreads();      // drains vmcnt -> counted region starts clean

  const int w    = tid >> 6;           // wave 0..3
  const int lane = tid & 63;
  // Staging sources. A: wave w owns rows w*64..w*64+63 (4 calls x 16 rows);
  // B: rows w*32..w*32+31 (2 calls). Per call, lane l covers row r0c+(l>>2),
  // slot l&3; pre-swizzled global quarter = (l&3)^((l>>3)&3).
  const int qsrc = (lane & 3) ^ ((lane >> 3) & 3);
  const int lr   = lane >> 2;
  const unsigned short* srcA0 = xb + (size_t)(tid_s[w * 64 +  0 + lr] >> 1) * DIM + qsrc * 8;
  const unsigned short* srcA1 = xb + (size_t)(tid_s[w * 64 + 16 + lr] >> 1) * DIM + qsrc * 8;
  const unsigned short* srcA2 = xb + (size_t)(tid_s[w * 64 + 32 + lr] >> 1) * DIM + qsrc * 8;
  const unsigned short* srcA3 = xb + (size_t)(tid_s[w * 64 + 48 + lr] >> 1) * DIM + qsrc * 8;
  const unsigned short* srcB0 = Wt + ((size_t)e * DIM + cT * 128 + w * 32 +  0 + lr) * DIM + qsrc * 8;
  const unsigned short* srcB1 = Wt + ((size_t)e * DIM + cT * 128 + w * 32 + 16 + lr) * DIM + qsrc * 8;

  const int wr = w >> 1, wc = w & 1;   // 2M x 2N wave grid, 128x64 out each
  const int mrow = lane & 15;
  const int qg   = lane >> 4;
  const int s8   = (qg ^ ((mrow >> 1) & 3)) * 8;   // verified conflict-free
  const int rdA  = (wr * 128 + mrow) * 32 + s8;    // + mt*512
  const int rdB  = (wc * 64 + mrow) * 32 + s8;     // + nt*512

  f32x4 acc[8][4];
#pragma unroll
  for (int i = 0; i < 8; ++i)
#pragma unroll
    for (int j = 0; j < 4; ++j)
      acc[i][j] = {0.f, 0.f, 0.f, 0.f};

  // prologue: tiles 0,1 -> bufs 0,1 (12 calls); wait tile 0 (6 left)
  STG(0, 0);
  STG(1, 1);
  WAITVM(6);
  __builtin_amdgcn_s_barrier();

  int bC = 0, bS = 2;
#pragma unroll 1
  for (int kt = 0; kt < 30; ++kt) {    // steady state: stage kt+2, compute kt
    STG(kt + 2, bS);
    CMP(bC);
    WAITVM(6);                         // tile kt+1 resident; kt+2 in flight
    __builtin_amdgcn_s_barrier();
    bC = (bC == 2) ? 0 : bC + 1;
    bS = (bS == 2) ? 0 : bS + 1;
  }
  CMP(0);                              // tile 30 (buf 0)
  WAITVM(0);                           // drain tile 31
  __builtin_amdgcn_s_barrier();
  CMP(1);                              // tile 31 (buf 1)

  // epilogue: C/D map col=lane&15, row=(lane>>4)*4+r
  const int colBase = cT * 128 + wc * 64 + mrow;
  float bias[4];
#pragma unroll
  for (int nt = 0; nt < 4; ++nt)
    bias[nt] = eb[(size_t)e * DIM + colBase + nt * 16];
#pragma unroll
  for (int mt = 0; mt < 8; ++mt) {
#pragma unroll
    for (int r = 0; r < 4; ++r) {
      const int rloc = wr * 128 + mt * 16 + (lane >> 4) * 4 + r;
      if (rloc < rows) {
        const int tk    = tid_s[rloc];
        const float wgt = w_s[rloc];
        __half* dst = yslot + ((size_t)(tk & 1) * TOK + (size_t)(tk >> 1)) * DIM;
#pragma unroll
        for (int nt = 0; nt < 4; ++nt)
          dst[colBase + nt * 16] = __float2half(wgt * (acc[mt][nt][r] + bias[nt]));
      }
    }
  }
}

__global__ __launch_bounds__(256) void combine(
    const __half* __restrict__ y0, const __half* __restrict__ y1,
    float4* __restrict__ out)
{
  const size_t i = (size_t)blockIdx.x * 256 + threadIdx.x;  // float4 index
  const ushort4 ua = ((const ushort4*)y0)[i];
  const ushort4 ub = ((const ushort4*)y1)[i];
  const __half* ah = (const __half*)&ua;
  const __half* bh = (const __half*)&ub;
  float4 o;
  o.x = __half2float(ah[0]) + __half2float(bh[0]);
  o.y = __half2float(ah[1]) + __half2float(bh[1]);
  o.z = __half2float(ah[2]) + __half2float(bh[2]);
  o.w = __half2float(ah[3]) + __half2float(bh[3]);
  out[i] = o;
}

extern "C" void kernel_launch(void* const* d_in, const int* in_sizes, int n_in,
                              void* d_out, int out_size, void* d_ws, size_t ws_size,
                              hipStream_t stream)
{
  const float* x  = (const float*)d_in[0];
  const float* gW = (const float*)d_in[1];
  const float* gb = (const float*)d_in[2];
  const float* eW = (const float*)d_in[3];
  const float* eb = (const float*)d_in[4];
  float* out = (float*)d_out;

  char* p = (char*)d_ws;
  unsigned short* xb = (unsigned short*)p;  p += (size_t)TOK * DIM * 2;       // 16 MB
  unsigned short* Wt = (unsigned short*)p;  p += (size_t)NE * DIM * DIM * 2;  // 16 MB
  __half* yslot = (__half*)p;               p += (size_t)2 * TOK * DIM * 2;   // 32 MB
  int* cnt = (int*)p;                       p += 256;
  int* listTok = (int*)p;                   p += (size_t)NE * TOK * 4;
  float* listW = (float*)p;                 p += (size_t)NE * TOK * 4;

  // eSel/wSel alias the head of yslot: consumed by scatter_kernel BEFORE
  // moe_gemm overwrites yslot (stream-ordered).
  int*   eSel = (int*)yslot;                        // TOK*2 ints = 64 KB
  float* wSel = (float*)((char*)yslot + TOK * 8);   // TOK*2 floats = 64 KB

  gate_kernel<<<TOK / 4, 256, 0, stream>>>(x, gW, gb, xb, eSel, wSel, cnt);
  scatter_kernel<<<TOK / 256, 256, 0, stream>>>(eSel, wSel, cnt, listTok, listW);
  transpose_w<<<NE * 256, 256, 0, stream>>>(eW, Wt);
  moe_gemm<<<NT * NCT, 256, 0, stream>>>(xb, Wt, eb, cnt, listTok, listW, yslot);
  combine<<<TOK * DIM / 4 / 256, 256, 0, stream>>>(
      yslot, yslot + (size_t)TOK * DIM, (float4*)out);
}

// Round 5
// 198.847 us; speedup vs baseline: 1.0768x; 1.0462x over previous
//
#include <hip/hip_runtime.h>
#include <hip/hip_fp16.h>
#include <stdint.h>

#define TOK 8192      // B*S
#define DIM 1024
#define NE 8
#define NT 72         // max 256-row tiles: 64 full + <=7 ragged (+1 safety)
#define NCT 8         // 1024 / 128 col-tiles

typedef short bf16x8 __attribute__((ext_vector_type(8)));
typedef float f32x4 __attribute__((ext_vector_type(4)));

__device__ __forceinline__ unsigned short f2bf(float f) {
  unsigned int u = __float_as_uint(f);
  u += 0x7FFFu + ((u >> 16) & 1u);
  return (unsigned short)(u >> 16);
}

__device__ __forceinline__ void gl_lds16(const void* g, void* l) {
  __builtin_amdgcn_global_load_lds(
      (__attribute__((address_space(1))) unsigned int*)(g),
      (__attribute__((address_space(3))) unsigned int*)(l), 16, 0, 0);
}

__device__ __forceinline__ unsigned lds_off(const void* p) {
  // generic -> LDS(AS3) pointer -> 32-bit LDS byte offset
  return (unsigned)(size_t)(__attribute__((address_space(3))) const void*)p;
}

// One wave per token: convert x row to bf16 + gating dots (fp64 acc) + write picks.
__global__ __launch_bounds__(256) void gate_kernel(
    const float* __restrict__ x, const float* __restrict__ gW,
    const float* __restrict__ gb, unsigned short* __restrict__ xb,
    int* __restrict__ eSel, float* __restrict__ wSel, int* __restrict__ cnt)
{
  if (blockIdx.x == 0 && threadIdx.x < NE) cnt[threadIdx.x] = 0;

  __shared__ float gWs[NE * DIM];   // 32 KB, [e][d]
#pragma unroll
  for (int h = 0; h < 8; ++h) {
    const int m = threadIdx.x + h * 256;       // float4 id over gW (2048)
    float4 v = ((const float4*)gW)[m];
    const int d = m >> 1, e0 = (m & 1) * 4;    // gW is [d][e]: elem 4m+c = (d, e0+c)
    gWs[(e0 + 0) * DIM + d] = v.x;
    gWs[(e0 + 1) * DIM + d] = v.y;
    gWs[(e0 + 2) * DIM + d] = v.z;
    gWs[(e0 + 3) * DIM + d] = v.w;
  }
  __syncthreads();

  const int wave = threadIdx.x >> 6;
  const int lane = threadIdx.x & 63;
  const int t = blockIdx.x * 4 + wave;
  const float4* xrow = (const float4*)(x + (size_t)t * DIM);
  ushort4* xbrow = (ushort4*)(xb + (size_t)t * DIM);

  double acc[NE];
#pragma unroll
  for (int e = 0; e < NE; ++e) acc[e] = 0.0;

#pragma unroll
  for (int i = 0; i < 4; ++i) {
    const int j = i * 64 + lane;         // float4 index within row (0..255)
    float4 v = xrow[j];
    ushort4 pk;
    pk.x = f2bf(v.x); pk.y = f2bf(v.y); pk.z = f2bf(v.z); pk.w = f2bf(v.w);
    xbrow[j] = pk;
#pragma unroll
    for (int e = 0; e < NE; ++e) {
      float4 gv = *(const float4*)&gWs[e * DIM + j * 4];
      acc[e] += (double)v.x * (double)gv.x + (double)v.y * (double)gv.y
              + (double)v.z * (double)gv.z + (double)v.w * (double)gv.w;
    }
  }
  // wave64 butterfly reduce (doubles)
#pragma unroll
  for (int off = 32; off > 0; off >>= 1) {
#pragma unroll
    for (int e = 0; e < NE; ++e)
      acc[e] += __shfl_xor(acc[e], off, 64);
  }

  if (lane == 0) {
    double s[NE];
#pragma unroll
    for (int e = 0; e < NE; ++e) {
      s[e] = acc[e] + (double)gb[e];
      if (s[e] < 1e-4) s[e] = 1e-4;     // clamp-min(EPS), TEMP=1
    }
    // top-2 by value on fp64 sums, ties -> lower index (strict > scan)
    int e0 = 0;
    for (int e = 1; e < NE; ++e) if (s[e] > s[e0]) e0 = e;
    int e1 = (e0 == 0) ? 1 : 0;
    for (int e = 0; e < NE; ++e) if (e != e0 && s[e] > s[e1]) e1 = e;
    // softmax + weights in fp32 (hardware exp)
    float m = (float)s[e0];             // e0 is the max
    float Z = 0.f, pf[NE];
#pragma unroll
    for (int e = 0; e < NE; ++e) { pf[e] = __expf((float)s[e] - m); Z += pf[e]; }
    float w0 = pf[e0] / Z; if (w0 < 0.1f) w0 = 0.1f;
    float w1 = pf[e1] / Z; if (w1 < 0.1f) w1 = 0.1f;
    const float inv = 0.5f / (w0 + w1);   // /total /K
    eSel[t * 2 + 0] = e0;
    eSel[t * 2 + 1] = e1;
    wSel[t * 2 + 0] = w0 * inv;
    wSel[t * 2 + 1] = w1 * inv;
  }
}

// Two-level scatter: LDS histogram per block, 8 global atomics per block.
__global__ __launch_bounds__(256) void scatter_kernel(
    const int* __restrict__ eSel, const float* __restrict__ wSel,
    int* __restrict__ cnt, int* __restrict__ listTok, float* __restrict__ listW)
{
  __shared__ int lcnt[NE];
  __shared__ int base[NE];
  const int tid = threadIdx.x;
  if (tid < NE) lcnt[tid] = 0;
  __syncthreads();

  const int t = blockIdx.x * 256 + tid;
  const int e0 = eSel[t * 2 + 0];
  const int e1 = eSel[t * 2 + 1];
  const float w0 = wSel[t * 2 + 0];
  const float w1 = wSel[t * 2 + 1];
  const int l0 = atomicAdd(&lcnt[e0], 1);
  const int l1 = atomicAdd(&lcnt[e1], 1);
  __syncthreads();
  if (tid < NE) base[tid] = atomicAdd(&cnt[tid], lcnt[tid]);
  __syncthreads();

  const int p0 = base[e0] + l0;
  listTok[e0 * TOK + p0] = t * 2 + 0;   // token*2 + slot
  listW [e0 * TOK + p0] = w0;
  const int p1 = base[e1] + l1;
  listTok[e1 * TOK + p1] = t * 2 + 1;
  listW [e1 * TOK + p1] = w1;
}

// expert_W [e][d][f] fp32 -> Wt [e][f][d] bf16. 64x64 LDS tiles, 2048 blocks,
// float4 coalesced loads, packed uint (2xbf16) stores.
__global__ __launch_bounds__(256) void transpose_w(
    const float* __restrict__ W, unsigned short* __restrict__ Wt)
{
  __shared__ float t2[64][65];           // +1 pad
  const int b  = blockIdx.x;
  const int e  = b >> 8;                 // 256 tiles per expert
  const int db = (b >> 4) & 15;          // d (k) block
  const int fb = b & 15;                 // f block
  const int d0 = db * 64, f0 = fb * 64;
  const int tid = threadIdx.x;
#pragma unroll
  for (int h = 0; h < 4; ++h) {
    const int idx = tid + h * 256;
    const int r = idx >> 4, c4 = idx & 15;
    float4 v = *(const float4*)&W[((size_t)e * DIM + d0 + r) * DIM + f0 + c4 * 4];
    t2[r][c4 * 4 + 0] = v.x;
    t2[r][c4 * 4 + 1] = v.y;
    t2[r][c4 * 4 + 2] = v.z;
    t2[r][c4 * 4 + 3] = v.w;
  }
  __syncthreads();
#pragma unroll
  for (int h = 0; h < 8; ++h) {
    const int o = tid + h * 256;
    const int f = o >> 5, k2 = (o & 31) * 2;
    const unsigned int lo = f2bf(t2[k2][f]);
    const unsigned int hi = f2bf(t2[k2 + 1][f]);
    *(unsigned int*)&Wt[((size_t)e * DIM + f0 + f) * DIM + d0 + k2] =
        lo | (hi << 16);
  }
}

// ---------------------------------------------------------------------------
// R11 moe_gemm: R10's geometry VERBATIM (256x128 tile, 4 waves, 128x64
// wave-tile, ring-3, counted vmcnt(6)). SINGLE change: the LDS->reg loads
// are now inline-asm ds_read_b128 (+ in-asm lgkmcnt(0)).
//
// Post-mortem R7-R10 (all 17-18% MfmaUtil, ~1400cy/iter unexplained stall):
// compiler-visible ds_reads after global_load_lds force hipcc to insert its
// own s_waitcnt vmcnt(0) before the read cluster (it cannot disambiguate the
// read from outstanding LDS-DMA writes) — draining the just-issued kt+2
// prefetch each iteration and exposing the full scattered-gather latency.
// This made R7 (syncthreads drain) == R8/R9/R10 ("counted", but re-drained).
// asm ds_read is opaque to that alias analysis: our vmcnt(6) becomes the
// only vmem wait in the loop, so the 2-tile prefetch (~2000cy) finally
// covers the ~900cy gather latency. MFMAs consume asm outputs -> SSA order
// guarantees they follow the in-asm lgkmcnt(0); sched_barrier(0) taken too.
// ---------------------------------------------------------------------------
#define WAITVM(n) asm volatile("s_waitcnt vmcnt(" #n ")" ::: "memory")

#define STG(kt, bs)                                                          \
  { const int off_ = (kt) * 32;                                              \
    gl_lds16(srcA0 + off_, &As[bs][w * 2048 + 0]);                           \
    gl_lds16(srcA1 + off_, &As[bs][w * 2048 + 512]);                         \
    gl_lds16(srcA2 + off_, &As[bs][w * 2048 + 1024]);                        \
    gl_lds16(srcA3 + off_, &As[bs][w * 2048 + 1536]);                        \
    gl_lds16(srcB0 + off_, &Bs[bs][w * 1024 + 0]);                           \
    gl_lds16(srcB1 + off_, &Bs[bs][w * 1024 + 512]); }

// A buffer stride 16384 B, B buffer stride 8192 B; mt/nt step = 512 elem = 1024 B
#define CMP(bs)                                                              \
  { const unsigned aA = asOff + (unsigned)(bs) * 16384u + rdA2;              \
    const unsigned bA = bsOff + (unsigned)(bs) * 8192u + rdB2;               \
    bf16x8 a0,a1,a2,a3,a4,a5,a6,a7,b0,b1,b2,b3;                              \
    asm volatile(                                                            \
      "ds_read_b128 %0, %12 offset:0\n\t"                                    \
      "ds_read_b128 %1, %12 offset:1024\n\t"                                 \
      "ds_read_b128 %2, %12 offset:2048\n\t"                                 \
      "ds_read_b128 %3, %12 offset:3072\n\t"                                 \
      "ds_read_b128 %4, %12 offset:4096\n\t"                                 \
      "ds_read_b128 %5, %12 offset:5120\n\t"                                 \
      "ds_read_b128 %6, %12 offset:6144\n\t"                                 \
      "ds_read_b128 %7, %12 offset:7168\n\t"                                 \
      "ds_read_b128 %8, %13 offset:0\n\t"                                    \
      "ds_read_b128 %9, %13 offset:1024\n\t"                                 \
      "ds_read_b128 %10, %13 offset:2048\n\t"                                \
      "ds_read_b128 %11, %13 offset:3072\n\t"                                \
      "s_waitcnt lgkmcnt(0)"                                                 \
      : "=&v"(a0),"=&v"(a1),"=&v"(a2),"=&v"(a3),                             \
        "=&v"(a4),"=&v"(a5),"=&v"(a6),"=&v"(a7),                             \
        "=&v"(b0),"=&v"(b1),"=&v"(b2),"=&v"(b3)                              \
      : "v"(aA), "v"(bA)                                                     \
      : "memory");                                                           \
    __builtin_amdgcn_sched_barrier(0);                                       \
    bf16x8 af[8] = {a0, a1, a2, a3, a4, a5, a6, a7};                         \
    bf16x8 bfr[4] = {b0, b1, b2, b3};                                        \
    __builtin_amdgcn_s_setprio(1);                                           \
    _Pragma("unroll")                                                        \
    for (int mt = 0; mt < 8; ++mt)                                           \
      _Pragma("unroll")                                                      \
      for (int nt = 0; nt < 4; ++nt)                                         \
        acc[mt][nt] = __builtin_amdgcn_mfma_f32_16x16x32_bf16(               \
            af[mt], bfr[nt], acc[mt][nt], 0, 0, 0);                          \
    __builtin_amdgcn_s_setprio(0); }

__global__ __launch_bounds__(256, 2) void moe_gemm(
    const unsigned short* __restrict__ xb, const unsigned short* __restrict__ Wt,
    const float* __restrict__ eb, const int* __restrict__ cnt,
    const int* __restrict__ listTok, const float* __restrict__ listW,
    __half* __restrict__ yslot)
{
  const int dId = blockIdx.x % NT;   // dId-major; NT%8==0 -> cT siblings share XCD
  const int cT  = blockIdx.x / NT;
  int e = -1, r0 = 0, rows = 0, accT = 0;
#pragma unroll
  for (int ee = 0; ee < NE; ++ee) {
    const int c = cnt[ee];
    const int nt = (c + 255) >> 8;
    if (dId >= accT && dId < accT + nt) {
      e = ee; r0 = (dId - accT) * 256;
      rows = c - r0; if (rows > 256) rows = 256;
    }
    accT += nt;
  }
  if (e < 0) return;   // block-uniform exit, before any barrier

  // ring-3: A 3x16KB, B 3x8KB, lists 2KB = 74KB -> 2 blocks/CU
  __shared__ __align__(16) unsigned short As[3][256 * 32];
  __shared__ __align__(16) unsigned short Bs[3][128 * 32];
  __shared__ int   tid_s[256];
  __shared__ float w_s[256];

  const int tid = threadIdx.x;
  if (tid < rows) {
    tid_s[tid] = listTok[e * TOK + r0 + tid];
    w_s[tid]   = listW [e * TOK + r0 + tid];
  } else {
    tid_s[tid] = 0;     // safe dummy row (token 0) — never stored
    w_s[tid]   = 0.0f;
  }
  __syncthreads();      // drains vmcnt -> counted region starts clean

  const int w    = tid >> 6;           // wave 0..3
  const int lane = tid & 63;
  // Staging sources. A: wave w owns rows w*64..w*64+63 (4 calls x 16 rows);
  // B: rows w*32..w*32+31 (2 calls). Per call, lane l covers row r0c+(l>>2),
  // slot l&3; pre-swizzled global quarter = (l&3)^((l>>3)&3).
  const int qsrc = (lane & 3) ^ ((lane >> 3) & 3);
  const int lr   = lane >> 2;
  const unsigned short* srcA0 = xb + (size_t)(tid_s[w * 64 +  0 + lr] >> 1) * DIM + qsrc * 8;
  const unsigned short* srcA1 = xb + (size_t)(tid_s[w * 64 + 16 + lr] >> 1) * DIM + qsrc * 8;
  const unsigned short* srcA2 = xb + (size_t)(tid_s[w * 64 + 32 + lr] >> 1) * DIM + qsrc * 8;
  const unsigned short* srcA3 = xb + (size_t)(tid_s[w * 64 + 48 + lr] >> 1) * DIM + qsrc * 8;
  const unsigned short* srcB0 = Wt + ((size_t)e * DIM + cT * 128 + w * 32 +  0 + lr) * DIM + qsrc * 8;
  const unsigned short* srcB1 = Wt + ((size_t)e * DIM + cT * 128 + w * 32 + 16 + lr) * DIM + qsrc * 8;

  const int wr = w >> 1, wc = w & 1;   // 2M x 2N wave grid, 128x64 out each
  const int mrow = lane & 15;
  const int qg   = lane >> 4;
  const int s8   = (qg ^ ((mrow >> 1) & 3)) * 8;   // verified conflict-free
  const unsigned rdA2 = (unsigned)(((wr * 128 + mrow) * 32 + s8) * 2);  // bytes
  const unsigned rdB2 = (unsigned)(((wc * 64 + mrow) * 32 + s8) * 2);   // bytes
  const unsigned asOff = lds_off(&As[0][0]);
  const unsigned bsOff = lds_off(&Bs[0][0]);

  f32x4 acc[8][4];
#pragma unroll
  for (int i = 0; i < 8; ++i)
#pragma unroll
    for (int j = 0; j < 4; ++j)
      acc[i][j] = {0.f, 0.f, 0.f, 0.f};

  // prologue: tiles 0,1 -> bufs 0,1 (12 calls); wait tile 0 (6 left)
  STG(0, 0);
  STG(1, 1);
  WAITVM(6);
  __builtin_amdgcn_s_barrier();

  int bC = 0, bS = 2;
#pragma unroll 1
  for (int kt = 0; kt < 30; ++kt) {    // steady state: stage kt+2, compute kt
    STG(kt + 2, bS);
    CMP(bC);
    WAITVM(6);                         // tile kt+1 resident; kt+2 in flight
    __builtin_amdgcn_s_barrier();
    bC = (bC == 2) ? 0 : bC + 1;
    bS = (bS == 2) ? 0 : bS + 1;
  }
  CMP(0);                              // tile 30 (buf 0)
  WAITVM(0);                           // drain tile 31
  __builtin_amdgcn_s_barrier();
  CMP(1);                              // tile 31 (buf 1)

  // epilogue: C/D map col=lane&15, row=(lane>>4)*4+r
  const int colBase = cT * 128 + wc * 64 + mrow;
  float bias[4];
#pragma unroll
  for (int nt = 0; nt < 4; ++nt)
    bias[nt] = eb[(size_t)e * DIM + colBase + nt * 16];
#pragma unroll
  for (int mt = 0; mt < 8; ++mt) {
#pragma unroll
    for (int r = 0; r < 4; ++r) {
      const int rloc = wr * 128 + mt * 16 + (lane >> 4) * 4 + r;
      if (rloc < rows) {
        const int tk    = tid_s[rloc];
        const float wgt = w_s[rloc];
        __half* dst = yslot + ((size_t)(tk & 1) * TOK + (size_t)(tk >> 1)) * DIM;
#pragma unroll
        for (int nt = 0; nt < 4; ++nt)
          dst[colBase + nt * 16] = __float2half(wgt * (acc[mt][nt][r] + bias[nt]));
      }
    }
  }
}

__global__ __launch_bounds__(256) void combine(
    const __half* __restrict__ y0, const __half* __restrict__ y1,
    float4* __restrict__ out)
{
  const size_t i = (size_t)blockIdx.x * 256 + threadIdx.x;  // float4 index
  const ushort4 ua = ((const ushort4*)y0)[i];
  const ushort4 ub = ((const ushort4*)y1)[i];
  const __half* ah = (const __half*)&ua;
  const __half* bh = (const __half*)&ub;
  float4 o;
  o.x = __half2float(ah[0]) + __half2float(bh[0]);
  o.y = __half2float(ah[1]) + __half2float(bh[1]);
  o.z = __half2float(ah[2]) + __half2float(bh[2]);
  o.w = __half2float(ah[3]) + __half2float(bh[3]);
  out[i] = o;
}

extern "C" void kernel_launch(void* const* d_in, const int* in_sizes, int n_in,
                              void* d_out, int out_size, void* d_ws, size_t ws_size,
                              hipStream_t stream)
{
  const float* x  = (const float*)d_in[0];
  const float* gW = (const float*)d_in[1];
  const float* gb = (const float*)d_in[2];
  const float* eW = (const float*)d_in[3];
  const float* eb = (const float*)d_in[4];
  float* out = (float*)d_out;

  char* p = (char*)d_ws;
  unsigned short* xb = (unsigned short*)p;  p += (size_t)TOK * DIM * 2;       // 16 MB
  unsigned short* Wt = (unsigned short*)p;  p += (size_t)NE * DIM * DIM * 2;  // 16 MB
  __half* yslot = (__half*)p;               p += (size_t)2 * TOK * DIM * 2;   // 32 MB
  int* cnt = (int*)p;                       p += 256;
  int* listTok = (int*)p;                   p += (size_t)NE * TOK * 4;
  float* listW = (float*)p;                 p += (size_t)NE * TOK * 4;

  // eSel/wSel alias the head of yslot: consumed by scatter_kernel BEFORE
  // moe_gemm overwrites yslot (stream-ordered).
  int*   eSel = (int*)yslot;                        // TOK*2 ints = 64 KB
  float* wSel = (float*)((char*)yslot + TOK * 8);   // TOK*2 floats = 64 KB

  gate_kernel<<<TOK / 4, 256, 0, stream>>>(x, gW, gb, xb, eSel, wSel, cnt);
  scatter_kernel<<<TOK / 256, 256, 0, stream>>>(eSel, wSel, cnt, listTok, listW);
  transpose_w<<<NE * 256, 256, 0, stream>>>(eW, Wt);
  moe_gemm<<<NT * NCT, 256, 0, stream>>>(xb, Wt, eb, cnt, listTok, listW, yslot);
  combine<<<TOK * DIM / 4 / 256, 256, 0, stream>>>(
      yslot, yslot + (size_t)TOK * DIM, (float4*)out);
}